// Round 1
// baseline (1214.505 us; speedup 1.0000x reference)
//
#include <hip/hip_runtime.h>
#include <stdint.h>

#define B_ 16
#define H_ 64
#define W_ 64
#define D_ 64
#define C_ 16
#define K_ 5
#define N_ 4096
#define EPS 1e-5f

__device__ __forceinline__ float wsum64(float v){
  #pragma unroll
  for(int o=1;o<64;o<<=1) v += __shfl_xor(v,o,64);
  return v;
}
__device__ __forceinline__ float wmax64(float v){
  #pragma unroll
  for(int o=1;o<64;o<<=1) v = fmaxf(v, __shfl_xor(v,o,64));
  return v;
}
__device__ __forceinline__ float wmin64(float v){
  #pragma unroll
  for(int o=1;o<64;o<<=1) v = fminf(v, __shfl_xor(v,o,64));
  return v;
}
__device__ __forceinline__ uint16_t f2bf(float f){
  uint32_t u = __float_as_uint(f);
  u += 0x7fffu + ((u>>16)&1u);
  return (uint16_t)(u>>16);
}

// slot = mu + exp(logsigma) * noise
__global__ void k_init_slot(const float* __restrict__ noise, const float* __restrict__ mu,
                            const float* __restrict__ ls, float* __restrict__ slot){
  int i = blockIdx.x*256 + threadIdx.x;
  if(i >= B_*K_*D_) return;
  int d = i & 63;
  slot[i] = mu[d] + expf(ls[d])*noise[i];
}

// fg_pos (K,2): weighted mean of grid under mask
__global__ void k_fgpos(const float* __restrict__ mask, float* __restrict__ ws_fg,
                        float* __restrict__ out_fg){
  int k = blockIdx.x; int tid = threadIdx.x;
  float sm=0.f, sx=0.f, sy=0.f;
  for(int p=tid; p<H_*W_; p+=256){
    int i=p>>6, j=p&63;
    float m = mask[k*H_*W_ + p];
    float x = -1.f + (2.f/63.f)*j;
    float y = -1.f + (2.f/63.f)*i;
    sm+=m; sx+=m*x; sy+=m*y;
  }
  __shared__ float r0[4], r1[4], r2[4];
  int wid=tid>>6, lane=tid&63;
  sm=wsum64(sm); sx=wsum64(sx); sy=wsum64(sy);
  if(lane==0){ r0[wid]=sm; r1[wid]=sx; r2[wid]=sy; }
  __syncthreads();
  if(tid==0){
    float tm=r0[0]+r0[1]+r0[2]+r0[3];
    float tx=r1[0]+r1[1]+r1[2]+r1[3];
    float ty=r2[0]+r2[1]+r2[2]+r2[3];
    float px = tx/(tm+1e-5f), py = ty/(tm+1e-5f);
    ws_fg[k*2+0]=px; ws_fg[k*2+1]=py;
    for(int b=0;b<B_;b++){ out_fg[(b*K_+k)*2+0]=px; out_fg[(b*K_+k)*2+1]=py; }
  }
}

// grid_embed (K,N,D): rel4 @ w_grid.T + b_grid, rel4=[rx,ry,-rx,-ry]
__global__ void k_gridemb(const float* __restrict__ wg, const float* __restrict__ bg,
                          const float* __restrict__ ws_fg, float* __restrict__ ge){
  int idx = blockIdx.x*256 + threadIdx.x;     // < K*N*D = 1310720
  int d = idx & 63;
  int n = (idx>>6) & (N_-1);
  int k = idx >> 18;
  int j = n & 63, i = n >> 6;
  float rx = (-1.f + (2.f/63.f)*j) - ws_fg[k*2+0];
  float ry = (-1.f + (2.f/63.f)*i) - ws_fg[k*2+1];
  ge[idx] = rx*(wg[d*4+0]-wg[d*4+2]) + ry*(wg[d*4+1]-wg[d*4+3]) + bg[d];
}

// feat LN + fk = featn@w_k.T, fv = featn@w_v.T  (one wave per row, lane=channel)
__global__ __launch_bounds__(256) void k_featln(const float* __restrict__ feat,
    const float* __restrict__ wk, const float* __restrict__ wv,
    const float* __restrict__ g, const float* __restrict__ bb,
    float* __restrict__ fk, float* __restrict__ fv){
  __shared__ float wTk[4096], wTv[4096];   // transposed: wT[d*64+d'] = w[d'][d]
  int tid=threadIdx.x;
  for(int i=tid;i<4096;i+=256){ int dp=i>>6, d=i&63; wTk[d*64+dp]=wk[i]; wTv[d*64+dp]=wv[i]; }
  __syncthreads();
  int wid=tid>>6, lane=tid&63;
  int base = blockIdx.x*16;
  float gg=g[lane], bbb=bb[lane];
  for(int i=0;i<4;i++){
    int r = base + i*4 + wid;
    float x = feat[(size_t)r*64+lane];
    float m = wsum64(x)*(1.f/64.f);
    float df = x-m;
    float var = wsum64(df*df)*(1.f/64.f);
    float xl = df*rsqrtf(var+EPS)*gg + bbb;
    float ak=0.f, av=0.f;
    #pragma unroll
    for(int d=0;d<64;d++){
      float xd = __shfl(xl,d,64);
      ak += xd*wTk[d*64+lane];
      av += xd*wTv[d*64+lane];
    }
    fk[(size_t)r*64+lane]=ak; fv[(size_t)r*64+lane]=av;
  }
}

// feat_color LN over C=16 (16 lanes per row)
__global__ void k_featcln(const float* __restrict__ fc, const float* __restrict__ g,
                          const float* __restrict__ b, float* __restrict__ out){
  int tid=threadIdx.x;
  int row = blockIdx.x*16 + (tid>>4);
  int c = tid&15;
  float x = fc[(size_t)row*16+c];
  float s=x;
  #pragma unroll
  for(int o=1;o<16;o<<=1) s += __shfl_xor(s,o,16);
  float m = s*(1.f/16.f);
  float df = x-m;
  float v2 = df*df;
  #pragma unroll
  for(int o=1;o<16;o<<=1) v2 += __shfl_xor(v2,o,16);
  out[(size_t)row*16+c] = df*rsqrtf(v2*(1.f/16.f)+EPS)*g[c] + b[c];
}

// K/V = LN(f{k,v}+ge)@w_mlp.T + b_mlp, stored bf16
__global__ __launch_bounds__(256) void k_buildkv(const float* __restrict__ fk,
    const float* __restrict__ fv, const float* __restrict__ ge,
    const float* __restrict__ lng, const float* __restrict__ lnb,
    const float* __restrict__ wm, const float* __restrict__ bm,
    uint16_t* __restrict__ Kw, uint16_t* __restrict__ Vw){
  __shared__ float wT[4096];
  int tid=threadIdx.x;
  for(int i=tid;i<4096;i+=256){ int dp=i>>6, d=i&63; wT[d*64+dp]=wm[i]; }
  __syncthreads();
  int wid=tid>>6, lane=tid&63;
  int nbase = blockIdx.x*16; int k=blockIdx.y; int b=blockIdx.z;
  float gg=lng[lane], bb2=lnb[lane], bml=bm[lane];
  for(int i=0;i<4;i++){
    int n = nbase + i*4 + wid;
    float gev = ge[((size_t)k*N_+n)*64+lane];
    size_t fidx = ((size_t)b*N_+n)*64+lane;
    size_t oidx = (((size_t)(b*K_+k))*N_+n)*64+lane;
    {
      float x = fk[fidx]+gev;
      float m=wsum64(x)*(1.f/64.f); float df=x-m;
      float var=wsum64(df*df)*(1.f/64.f);
      float xl=df*rsqrtf(var+EPS)*gg+bb2;
      float a=bml;
      #pragma unroll
      for(int d=0;d<64;d++) a += __shfl(xl,d,64)*wT[d*64+lane];
      Kw[oidx]=f2bf(a);
    }
    {
      float x = fv[fidx]+gev;
      float m=wsum64(x)*(1.f/64.f); float df=x-m;
      float var=wsum64(df*df)*(1.f/64.f);
      float xl=df*rsqrtf(var+EPS)*gg+bb2;
      float a=bml;
      #pragma unroll
      for(int d=0;d<64;d++) a += __shfl(xl,d,64)*wT[d*64+lane];
      Vw[oidx]=f2bf(a);
    }
  }
}

// q = LN(slot)@w_q.T, pre-scaled by d^-0.5
__global__ __launch_bounds__(64) void k_q(const float* __restrict__ slot,
    const float* __restrict__ g, const float* __restrict__ b,
    const float* __restrict__ wq, float* __restrict__ q){
  int row=blockIdx.x; int lane=threadIdx.x;
  float x = slot[row*64+lane];
  float m=wsum64(x)*(1.f/64.f); float df=x-m;
  float var=wsum64(df*df)*(1.f/64.f);
  float xl=df*rsqrtf(var+EPS)*g[lane]+b[lane];
  float a=0.f;
  #pragma unroll
  for(int d=0;d<64;d++) a += __shfl(xl,d,64)*wq[lane*64+d];
  q[row*64+lane]=a*0.125f;
}

// attention: logits, softmax, and (non-final) upd=attn@V  or (final) outputs
template<bool FINAL>
__global__ __launch_bounds__(1024) void k_attn(const uint16_t* __restrict__ Kw,
    const uint16_t* __restrict__ Vw, const float* __restrict__ q,
    const float* __restrict__ featc, const float* __restrict__ slot,
    float* __restrict__ upd, float* __restrict__ out_slot, float* __restrict__ out_attn){
  __shared__ float ls[4096];
  __shared__ float qs[64];
  __shared__ float red[34];
  __shared__ float part[1024];
  int tid=threadIdx.x; int bk=blockIdx.x; int b = bk / K_;
  int wid=tid>>6, lane=tid&63;
  if(tid<64) qs[tid]=q[bk*64+tid];
  __syncthreads();

  float lmax=-1e30f, lmin=1e30f;
  float lv[4];
  const uint4* Kb = (const uint4*)(Kw + (size_t)bk*N_*64);
  #pragma unroll
  for(int i=0;i<4;i++){
    int n = tid + i*1024;
    float a=0.f;
    #pragma unroll
    for(int j=0;j<8;j++){
      uint4 u = Kb[(size_t)n*8+j];
      a += __uint_as_float(u.x<<16)          * qs[j*8+0]
         + __uint_as_float(u.x&0xffff0000u)  * qs[j*8+1]
         + __uint_as_float(u.y<<16)          * qs[j*8+2]
         + __uint_as_float(u.y&0xffff0000u)  * qs[j*8+3]
         + __uint_as_float(u.z<<16)          * qs[j*8+4]
         + __uint_as_float(u.z&0xffff0000u)  * qs[j*8+5]
         + __uint_as_float(u.w<<16)          * qs[j*8+6]
         + __uint_as_float(u.w&0xffff0000u)  * qs[j*8+7];
    }
    lv[i]=a; ls[n]=a;
    lmax=fmaxf(lmax,a);
    if(FINAL) lmin=fminf(lmin,a);
  }
  // block max (and min if FINAL)
  float wm_=wmax64(lmax);
  if(lane==0) red[wid]=wm_;
  if(FINAL){ float wn_=wmin64(lmin); if(lane==0) red[16+wid]=wn_; }
  __syncthreads();
  if(tid==0){
    float a=red[0]; for(int i=1;i<16;i++) a=fmaxf(a,red[i]); red[32]=a;
    if(FINAL){ float c=red[16]; for(int i=1;i<16;i++) c=fminf(c,red[16+i]); red[33]=c; }
  }
  __syncthreads();
  float LMAX=red[32];
  float LMIN=FINAL?red[33]:0.f;
  // exp + block sum (red[0..15] disjoint from red[32..33])
  float s=0.f;
  #pragma unroll
  for(int i=0;i<4;i++){
    int n=tid+i*1024;
    float e=__expf(lv[i]-LMAX);
    ls[n]=e; s+=e;
  }
  s=wsum64(s);
  if(lane==0) red[wid]=s;
  __syncthreads();
  if(tid==0){ float a=0.f; for(int i=0;i<16;i++) a+=red[i]; red[32]=a; }
  __syncthreads();
  float inv = 1.f/red[32];

  if(!FINAL){
    int sub=lane>>4, c4=lane&15;
    const uint2* Vb = (const uint2*)(Vw + (size_t)bk*N_*64);
    float a0=0.f,a1=0.f,a2=0.f,a3=0.f;
    for(int t=0;t<64;t++){
      int n=(wid<<8)+(t<<2)+sub;
      float e=ls[n];
      uint2 u=Vb[(size_t)n*16+c4];
      a0+=e*__uint_as_float(u.x<<16);
      a1+=e*__uint_as_float(u.x&0xffff0000u);
      a2+=e*__uint_as_float(u.y<<16);
      a3+=e*__uint_as_float(u.y&0xffff0000u);
    }
    a0+=__shfl_xor(a0,16,64); a0+=__shfl_xor(a0,32,64);
    a1+=__shfl_xor(a1,16,64); a1+=__shfl_xor(a1,32,64);
    a2+=__shfl_xor(a2,16,64); a2+=__shfl_xor(a2,32,64);
    a3+=__shfl_xor(a3,16,64); a3+=__shfl_xor(a3,32,64);
    if(lane<16){
      part[wid*64+lane*4+0]=a0; part[wid*64+lane*4+1]=a1;
      part[wid*64+lane*4+2]=a2; part[wid*64+lane*4+3]=a3;
    }
    __syncthreads();
    if(tid<64){
      float s2=0.f;
      #pragma unroll
      for(int w=0;w<16;w++) s2+=part[w*64+tid];
      upd[bk*64+tid]=s2*inv;
    }
  } else {
    // normalized attention output
    float amax = inv;                        // exp(0)*inv
    float amin = __expf(LMIN-LMAX)*inv;
    float dinv = 1.f/(amax-amin+1e-5f);
    #pragma unroll
    for(int i=0;i<4;i++){
      int n=tid+i*1024;
      out_attn[(size_t)bk*N_+n] = (ls[n]*inv - amin)*dinv;
    }
    // slot_color = attn @ featc_n
    int sub=lane>>4, c=lane&15;
    const float* Fb = featc + (size_t)b*N_*16;
    float a0=0.f;
    for(int t=0;t<64;t++){
      int n=(wid<<8)+(t<<2)+sub;
      a0 += ls[n]*Fb[(size_t)n*16+c];
    }
    a0+=__shfl_xor(a0,16,64); a0+=__shfl_xor(a0,32,64);
    if(lane<16) part[wid*16+lane]=a0;
    __syncthreads();
    if(tid<16){
      float s2=0.f;
      #pragma unroll
      for(int w=0;w<16;w++) s2+=part[w*16+tid];
      out_slot[bk*80+64+tid]=s2*inv;
    }
    if(tid<64) out_slot[bk*80+tid]=slot[bk*64+tid];
  }
}

// GRU cell + LN residual projection
__global__ __launch_bounds__(64) void k_gru(const float* __restrict__ upd, float* __restrict__ slot,
   const float* __restrict__ wih, const float* __restrict__ whh,
   const float* __restrict__ bih, const float* __restrict__ bhh,
   const float* __restrict__ lng, const float* __restrict__ lnb,
   const float* __restrict__ wres, const float* __restrict__ bres){
  int row=blockIdx.x; int lane=threadIdx.x;
  float x=upd[row*64+lane], hp=slot[row*64+lane];
  float gir=bih[lane], giz=bih[64+lane], gin=bih[128+lane];
  float ghr=bhh[lane], ghz=bhh[64+lane], ghn=bhh[128+lane];
  #pragma unroll
  for(int d=0;d<64;d++){
    float xd=__shfl(x,d,64), hd=__shfl(hp,d,64);
    gir+=xd*wih[lane*64+d];
    giz+=xd*wih[(64+lane)*64+d];
    gin+=xd*wih[(128+lane)*64+d];
    ghr+=hd*whh[lane*64+d];
    ghz+=hd*whh[(64+lane)*64+d];
    ghn+=hd*whh[(128+lane)*64+d];
  }
  float r=1.f/(1.f+expf(-(gir+ghr)));
  float z=1.f/(1.f+expf(-(giz+ghz)));
  float nn=tanhf(gin+r*ghn);
  float sp=(1.f-z)*nn+z*hp;
  float m=wsum64(sp)*(1.f/64.f); float df=sp-m;
  float var=wsum64(df*df)*(1.f/64.f);
  float xl=df*rsqrtf(var+EPS)*lng[lane]+lnb[lane];
  float a=bres[lane]+hp;
  #pragma unroll
  for(int d=0;d<64;d++) a+=__shfl(xl,d,64)*wres[lane*64+d];
  slot[row*64+lane]=a;
}

extern "C" void kernel_launch(void* const* d_in, const int* in_sizes, int n_in,
                              void* d_out, int out_size, void* d_ws, size_t ws_size,
                              hipStream_t stream){
  (void)in_sizes; (void)n_in; (void)out_size; (void)ws_size;
  const float* feat = (const float*)d_in[0];
  const float* featc= (const float*)d_in[1];
  const float* mask = (const float*)d_in[2];
  const float* noise= (const float*)d_in[3];
  const float* mu   = (const float*)d_in[4];
  const float* lsg  = (const float*)d_in[5];
  const float* wg   = (const float*)d_in[6];
  const float* bg   = (const float*)d_in[7];
  const float* wk   = (const float*)d_in[8];
  const float* wv   = (const float*)d_in[9];
  const float* lnkg = (const float*)d_in[10];
  const float* lnkb = (const float*)d_in[11];
  const float* wm   = (const float*)d_in[12];
  const float* bm   = (const float*)d_in[13];
  const float* lnqg = (const float*)d_in[14];
  const float* lnqb = (const float*)d_in[15];
  const float* wq   = (const float*)d_in[16];
  const float* wih  = (const float*)d_in[17];
  const float* whh  = (const float*)d_in[18];
  const float* bih  = (const float*)d_in[19];
  const float* bhh  = (const float*)d_in[20];
  const float* lnfg = (const float*)d_in[21];
  const float* lnfb = (const float*)d_in[22];
  const float* lncg = (const float*)d_in[23];
  const float* lncb = (const float*)d_in[24];
  const float* lnrg = (const float*)d_in[25];
  const float* lnrb = (const float*)d_in[26];
  const float* wres = (const float*)d_in[27];
  const float* bres = (const float*)d_in[28];

  float* out = (float*)d_out;
  float* out_slot = out;          // (B,K,80)
  float* out_fg   = out + 6400;   // (B,K,2)
  float* out_attn = out + 6560;   // (B,K,N)

  float* wsf    = (float*)d_ws;
  float* ws_fg  = wsf;                     // 16
  float* ws_ge  = wsf + 16;                // K*N*D
  float* ws_fk  = ws_ge + (size_t)K_*N_*D_;
  float* ws_fv  = ws_fk + (size_t)B_*N_*D_;
  float* ws_fc  = ws_fv + (size_t)B_*N_*D_;
  float* ws_sl  = ws_fc + (size_t)B_*N_*C_;
  float* ws_q   = ws_sl + B_*K_*D_;
  float* ws_up  = ws_q  + B_*K_*D_;
  uint16_t* wsK = (uint16_t*)(ws_up + B_*K_*D_);
  uint16_t* wsV = wsK + (size_t)B_*K_*N_*D_;

  k_init_slot<<<20,256,0,stream>>>(noise,mu,lsg,ws_sl);
  k_fgpos<<<K_,256,0,stream>>>(mask,ws_fg,out_fg);
  k_gridemb<<<(K_*N_*D_)/256,256,0,stream>>>(wg,bg,ws_fg,ws_ge);
  k_featln<<<(B_*N_)/16,256,0,stream>>>(feat,wk,wv,lnfg,lnfb,ws_fk,ws_fv);
  k_featcln<<<(B_*N_)/16,256,0,stream>>>(featc,lncg,lncb,ws_fc);
  k_buildkv<<<dim3(N_/16,K_,B_),256,0,stream>>>(ws_fk,ws_fv,ws_ge,lnkg,lnkb,wm,bm,wsK,wsV);

  for(int it=0; it<4; it++){
    k_q<<<B_*K_,64,0,stream>>>(ws_sl,lnqg,lnqb,wq,ws_q);
    if(it<3){
      k_attn<false><<<B_*K_,1024,0,stream>>>(wsK,wsV,ws_q,ws_fc,ws_sl,ws_up,out_slot,out_attn);
      k_gru<<<B_*K_,64,0,stream>>>(ws_up,ws_sl,wih,whh,bih,bhh,lnrg,lnrb,wres,bres);
    } else {
      k_attn<true><<<B_*K_,1024,0,stream>>>(wsK,wsV,ws_q,ws_fc,ws_sl,ws_up,out_slot,out_attn);
    }
  }
}

// Round 2
// 469.078 us; speedup vs baseline: 2.5891x; 2.5891x over previous
//
#include <hip/hip_runtime.h>
#include <stdint.h>

#define B_ 16
#define H_ 64
#define W_ 64
#define D_ 64
#define C_ 16
#define K_ 5
#define N_ 4096
#define EPS 1e-5f

typedef __attribute__((ext_vector_type(8))) short bf16x8;
typedef __attribute__((ext_vector_type(4))) float f32x4;

__device__ __forceinline__ float wsum64(float v){
  #pragma unroll
  for(int o=1;o<64;o<<=1) v += __shfl_xor(v,o,64);
  return v;
}
__device__ __forceinline__ float wmax64(float v){
  #pragma unroll
  for(int o=1;o<64;o<<=1) v = fmaxf(v, __shfl_xor(v,o,64));
  return v;
}
__device__ __forceinline__ float wmin64(float v){
  #pragma unroll
  for(int o=1;o<64;o<<=1) v = fminf(v, __shfl_xor(v,o,64));
  return v;
}
__device__ __forceinline__ uint16_t f2bf(float f){
  uint32_t u = __float_as_uint(f);
  u += 0x7fffu + ((u>>16)&1u);
  return (uint16_t)(u>>16);
}

// slot = mu + exp(logsigma) * noise
__global__ void k_init_slot(const float* __restrict__ noise, const float* __restrict__ mu,
                            const float* __restrict__ ls, float* __restrict__ slot){
  int i = blockIdx.x*256 + threadIdx.x;
  if(i >= B_*K_*D_) return;
  int d = i & 63;
  slot[i] = mu[d] + expf(ls[d])*noise[i];
}

// fg_pos (K,2): weighted mean of grid under mask
__global__ void k_fgpos(const float* __restrict__ mask, float* __restrict__ ws_fg,
                        float* __restrict__ out_fg){
  int k = blockIdx.x; int tid = threadIdx.x;
  float sm=0.f, sx=0.f, sy=0.f;
  for(int p=tid; p<H_*W_; p+=256){
    int i=p>>6, j=p&63;
    float m = mask[k*H_*W_ + p];
    float x = -1.f + (2.f/63.f)*j;
    float y = -1.f + (2.f/63.f)*i;
    sm+=m; sx+=m*x; sy+=m*y;
  }
  __shared__ float r0[4], r1[4], r2[4];
  int wid=tid>>6, lane=tid&63;
  sm=wsum64(sm); sx=wsum64(sx); sy=wsum64(sy);
  if(lane==0){ r0[wid]=sm; r1[wid]=sx; r2[wid]=sy; }
  __syncthreads();
  if(tid==0){
    float tm=r0[0]+r0[1]+r0[2]+r0[3];
    float tx=r1[0]+r1[1]+r1[2]+r1[3];
    float ty=r2[0]+r2[1]+r2[2]+r2[3];
    float px = tx/(tm+1e-5f), py = ty/(tm+1e-5f);
    ws_fg[k*2+0]=px; ws_fg[k*2+1]=py;
    for(int b=0;b<B_;b++){ out_fg[(b*K_+k)*2+0]=px; out_fg[(b*K_+k)*2+1]=py; }
  }
}

// grid_embed (K,N,D): rel4 @ w_grid.T + b_grid, rel4=[rx,ry,-rx,-ry]
__global__ void k_gridemb(const float* __restrict__ wg, const float* __restrict__ bg,
                          const float* __restrict__ ws_fg, float* __restrict__ ge){
  int idx = blockIdx.x*256 + threadIdx.x;     // < K*N*D = 1310720
  int d = idx & 63;
  int n = (idx>>6) & (N_-1);
  int k = idx >> 18;
  int j = n & 63, i = n >> 6;
  float rx = (-1.f + (2.f/63.f)*j) - ws_fg[k*2+0];
  float ry = (-1.f + (2.f/63.f)*i) - ws_fg[k*2+1];
  ge[idx] = rx*(wg[d*4+0]-wg[d*4+2]) + ry*(wg[d*4+1]-wg[d*4+3]) + bg[d];
}

// feat LN + fk = featn@w_k.T, fv = featn@w_v.T  -- MFMA version.
// Wave owns 16 rows. lane: c=lane&15 -> row (B-frag col / X row), q=lane>>4.
// X B-frag: B[k=q*8+j][n=c] = xl[row c][ch q*8+j(+32)]  (lane loads exactly those ch)
// W A-frag: A[m=c -> out ch ot*16+c][k=q*8+j(+32)]
// D: lane holds Y[row nb+c][out ot*16+q*4+r], r=0..3 consecutive -> float4 store.
__global__ __launch_bounds__(256) void k_featln(const float* __restrict__ feat,
    const float* __restrict__ wk, const float* __restrict__ wv,
    const float* __restrict__ g, const float* __restrict__ bb,
    float* __restrict__ fk, float* __restrict__ fv){
  int tid=threadIdx.x, wid=tid>>6, lane=tid&63;
  int q=lane>>4, c=lane&15;
  size_t row = (size_t)blockIdx.x*64 + wid*16 + c;
  const float* xp = feat + row*64;
  float x[16];
  *(float4*)&x[0]  = *(const float4*)(xp + q*8);
  *(float4*)&x[4]  = *(const float4*)(xp + q*8 + 4);
  *(float4*)&x[8]  = *(const float4*)(xp + 32 + q*8);
  *(float4*)&x[12] = *(const float4*)(xp + 36 + q*8);
  float s=0.f;
  #pragma unroll
  for(int i=0;i<16;i++) s+=x[i];
  s += __shfl_xor(s,16,64); s += __shfl_xor(s,32,64);
  float mean = s*(1.f/64.f);
  float v=0.f;
  #pragma unroll
  for(int i=0;i<16;i++){ float d=x[i]-mean; v+=d*d; }
  v += __shfl_xor(v,16,64); v += __shfl_xor(v,32,64);
  float rs = rsqrtf(v*(1.f/64.f)+EPS);
  float gl[16], bl[16];
  *(float4*)&gl[0]  = *(const float4*)(g + q*8);
  *(float4*)&gl[4]  = *(const float4*)(g + q*8 + 4);
  *(float4*)&gl[8]  = *(const float4*)(g + 32 + q*8);
  *(float4*)&gl[12] = *(const float4*)(g + 36 + q*8);
  *(float4*)&bl[0]  = *(const float4*)(bb + q*8);
  *(float4*)&bl[4]  = *(const float4*)(bb + q*8 + 4);
  *(float4*)&bl[8]  = *(const float4*)(bb + 32 + q*8);
  *(float4*)&bl[12] = *(const float4*)(bb + 36 + q*8);
  bf16x8 A0, A1;
  #pragma unroll
  for(int j=0;j<8;j++){
    A0[j] = (short)f2bf((x[j]  -mean)*rs*gl[j]  +bl[j]);
    A1[j] = (short)f2bf((x[8+j]-mean)*rs*gl[8+j]+bl[8+j]);
  }
  #pragma unroll
  for(int mat=0;mat<2;mat++){
    const float* w = mat? wv : wk;
    float* o = (mat? fv : fk) + row*64;
    #pragma unroll
    for(int ot=0; ot<4; ot++){
      const float* wp = w + (size_t)(ot*16+c)*64 + q*8;
      bf16x8 W0, W1;
      #pragma unroll
      for(int j=0;j<8;j++){ W0[j]=(short)f2bf(wp[j]); W1[j]=(short)f2bf(wp[32+j]); }
      f32x4 acc = {0.f,0.f,0.f,0.f};
      acc = __builtin_amdgcn_mfma_f32_16x16x32_bf16(W0, A0, acc, 0,0,0);
      acc = __builtin_amdgcn_mfma_f32_16x16x32_bf16(W1, A1, acc, 0,0,0);
      *(f32x4*)(o + ot*16 + q*4) = acc;
    }
  }
}

// feat_color LN over C=16 (16 lanes per row)
__global__ void k_featcln(const float* __restrict__ fc, const float* __restrict__ g,
                          const float* __restrict__ b, float* __restrict__ out){
  int tid=threadIdx.x;
  int row = blockIdx.x*16 + (tid>>4);
  int c = tid&15;
  float x = fc[(size_t)row*16+c];
  float s=x;
  #pragma unroll
  for(int o=1;o<16;o<<=1) s += __shfl_xor(s,o,16);
  float m = s*(1.f/16.f);
  float df = x-m;
  float v2 = df*df;
  #pragma unroll
  for(int o=1;o<16;o<<=1) v2 += __shfl_xor(v2,o,16);
  out[(size_t)row*16+c] = df*rsqrtf(v2*(1.f/16.f)+EPS)*g[c] + b[c];
}

// K/V = LN(f{k,v}+ge)@w_mlp.T + b_mlp, stored bf16 -- MFMA version (see k_featln).
__global__ __launch_bounds__(256) void k_buildkv(const float* __restrict__ fk,
    const float* __restrict__ fv, const float* __restrict__ ge,
    const float* __restrict__ lng, const float* __restrict__ lnb,
    const float* __restrict__ wm, const float* __restrict__ bm,
    uint16_t* __restrict__ Kw, uint16_t* __restrict__ Vw){
  int tid=threadIdx.x, wid=tid>>6, lane=tid&63;
  int q=lane>>4, c=lane&15;
  int nb = blockIdx.x*64 + wid*16;
  int k = blockIdx.y, b = blockIdx.z;
  int n = nb + c;
  // W A-frags (shared by K and V paths)
  bf16x8 Wf[4][2];
  #pragma unroll
  for(int ot=0;ot<4;ot++){
    const float* wp = wm + (size_t)(ot*16+c)*64 + q*8;
    #pragma unroll
    for(int j=0;j<8;j++){ Wf[ot][0][j]=(short)f2bf(wp[j]); Wf[ot][1][j]=(short)f2bf(wp[32+j]); }
  }
  float bmv[4][4];
  #pragma unroll
  for(int ot=0;ot<4;ot++) *(float4*)&bmv[ot][0] = *(const float4*)(bm + ot*16 + q*4);
  float gl[16], bl[16];
  *(float4*)&gl[0]  = *(const float4*)(lng + q*8);
  *(float4*)&gl[4]  = *(const float4*)(lng + q*8 + 4);
  *(float4*)&gl[8]  = *(const float4*)(lng + 32 + q*8);
  *(float4*)&gl[12] = *(const float4*)(lng + 36 + q*8);
  *(float4*)&bl[0]  = *(const float4*)(lnb + q*8);
  *(float4*)&bl[4]  = *(const float4*)(lnb + q*8 + 4);
  *(float4*)&bl[8]  = *(const float4*)(lnb + 32 + q*8);
  *(float4*)&bl[12] = *(const float4*)(lnb + 36 + q*8);
  const float* gp = ge + ((size_t)k*N_ + n)*64;
  float ga[16];
  *(float4*)&ga[0]  = *(const float4*)(gp + q*8);
  *(float4*)&ga[4]  = *(const float4*)(gp + q*8 + 4);
  *(float4*)&ga[8]  = *(const float4*)(gp + 32 + q*8);
  *(float4*)&ga[12] = *(const float4*)(gp + 36 + q*8);
  #pragma unroll
  for(int mat=0;mat<2;mat++){
    const float* fp = (mat? fv : fk) + ((size_t)b*N_ + n)*64;
    float x[16];
    *(float4*)&x[0]  = *(const float4*)(fp + q*8);
    *(float4*)&x[4]  = *(const float4*)(fp + q*8 + 4);
    *(float4*)&x[8]  = *(const float4*)(fp + 32 + q*8);
    *(float4*)&x[12] = *(const float4*)(fp + 36 + q*8);
    #pragma unroll
    for(int i=0;i<16;i++) x[i]+=ga[i];
    float s=0.f;
    #pragma unroll
    for(int i=0;i<16;i++) s+=x[i];
    s += __shfl_xor(s,16,64); s += __shfl_xor(s,32,64);
    float mean = s*(1.f/64.f);
    float v=0.f;
    #pragma unroll
    for(int i=0;i<16;i++){ float d=x[i]-mean; v+=d*d; }
    v += __shfl_xor(v,16,64); v += __shfl_xor(v,32,64);
    float rs = rsqrtf(v*(1.f/64.f)+EPS);
    bf16x8 A0, A1;
    #pragma unroll
    for(int j=0;j<8;j++){
      A0[j] = (short)f2bf((x[j]  -mean)*rs*gl[j]  +bl[j]);
      A1[j] = (short)f2bf((x[8+j]-mean)*rs*gl[8+j]+bl[8+j]);
    }
    uint16_t* outb = (mat? Vw : Kw) + (((size_t)(b*K_+k))*N_)*64;
    #pragma unroll
    for(int ot=0; ot<4; ot++){
      f32x4 acc = {0.f,0.f,0.f,0.f};
      acc = __builtin_amdgcn_mfma_f32_16x16x32_bf16(Wf[ot][0], A0, acc, 0,0,0);
      acc = __builtin_amdgcn_mfma_f32_16x16x32_bf16(Wf[ot][1], A1, acc, 0,0,0);
      uint2 u;
      u.x = (uint32_t)f2bf(acc[0]+bmv[ot][0]) | ((uint32_t)f2bf(acc[1]+bmv[ot][1])<<16);
      u.y = (uint32_t)f2bf(acc[2]+bmv[ot][2]) | ((uint32_t)f2bf(acc[3]+bmv[ot][3])<<16);
      *(uint2*)(outb + (size_t)n*64 + ot*16 + q*4) = u;
    }
  }
}

// q = LN(slot)@w_q.T, pre-scaled by d^-0.5
__global__ __launch_bounds__(64) void k_q(const float* __restrict__ slot,
    const float* __restrict__ g, const float* __restrict__ b,
    const float* __restrict__ wq, float* __restrict__ q){
  int row=blockIdx.x; int lane=threadIdx.x;
  float x = slot[row*64+lane];
  float m=wsum64(x)*(1.f/64.f); float df=x-m;
  float var=wsum64(df*df)*(1.f/64.f);
  float xl=df*rsqrtf(var+EPS)*g[lane]+b[lane];
  float a=0.f;
  #pragma unroll
  for(int d=0;d<64;d++) a += __shfl(xl,d,64)*wq[lane*64+d];
  q[row*64+lane]=a*0.125f;
}

// attention: logits, softmax, and (non-final) upd=attn@V  or (final) outputs
template<bool FINAL>
__global__ __launch_bounds__(1024) void k_attn(const uint16_t* __restrict__ Kw,
    const uint16_t* __restrict__ Vw, const float* __restrict__ q,
    const float* __restrict__ featc, const float* __restrict__ slot,
    float* __restrict__ upd, float* __restrict__ out_slot, float* __restrict__ out_attn){
  __shared__ float ls[4096];
  __shared__ float qs[64];
  __shared__ float red[34];
  __shared__ float part[1024];
  int tid=threadIdx.x; int bk=blockIdx.x; int b = bk / K_;
  int wid=tid>>6, lane=tid&63;
  if(tid<64) qs[tid]=q[bk*64+tid];
  __syncthreads();

  float lmax=-1e30f, lmin=1e30f;
  float lv[4];
  const uint4* Kb = (const uint4*)(Kw + (size_t)bk*N_*64);
  #pragma unroll
  for(int i=0;i<4;i++){
    int n = tid + i*1024;
    float a=0.f;
    #pragma unroll
    for(int j=0;j<8;j++){
      uint4 u = Kb[(size_t)n*8+j];
      a += __uint_as_float(u.x<<16)          * qs[j*8+0]
         + __uint_as_float(u.x&0xffff0000u)  * qs[j*8+1]
         + __uint_as_float(u.y<<16)          * qs[j*8+2]
         + __uint_as_float(u.y&0xffff0000u)  * qs[j*8+3]
         + __uint_as_float(u.z<<16)          * qs[j*8+4]
         + __uint_as_float(u.z&0xffff0000u)  * qs[j*8+5]
         + __uint_as_float(u.w<<16)          * qs[j*8+6]
         + __uint_as_float(u.w&0xffff0000u)  * qs[j*8+7];
    }
    lv[i]=a; ls[n]=a;
    lmax=fmaxf(lmax,a);
    if(FINAL) lmin=fminf(lmin,a);
  }
  float wm_=wmax64(lmax);
  if(lane==0) red[wid]=wm_;
  if(FINAL){ float wn_=wmin64(lmin); if(lane==0) red[16+wid]=wn_; }
  __syncthreads();
  if(tid==0){
    float a=red[0]; for(int i=1;i<16;i++) a=fmaxf(a,red[i]); red[32]=a;
    if(FINAL){ float c=red[16]; for(int i=1;i<16;i++) c=fminf(c,red[16+i]); red[33]=c; }
  }
  __syncthreads();
  float LMAX=red[32];
  float LMIN=FINAL?red[33]:0.f;
  float s=0.f;
  #pragma unroll
  for(int i=0;i<4;i++){
    int n=tid+i*1024;
    float e=__expf(lv[i]-LMAX);
    ls[n]=e; s+=e;
  }
  s=wsum64(s);
  if(lane==0) red[wid]=s;
  __syncthreads();
  if(tid==0){ float a=0.f; for(int i=0;i<16;i++) a+=red[i]; red[32]=a; }
  __syncthreads();
  float inv = 1.f/red[32];

  if(!FINAL){
    int sub=lane>>4, c4=lane&15;
    const uint2* Vb = (const uint2*)(Vw + (size_t)bk*N_*64);
    float a0=0.f,a1=0.f,a2=0.f,a3=0.f;
    for(int t=0;t<64;t++){
      int n=(wid<<8)+(t<<2)+sub;
      float e=ls[n];
      uint2 u=Vb[(size_t)n*16+c4];
      a0+=e*__uint_as_float(u.x<<16);
      a1+=e*__uint_as_float(u.x&0xffff0000u);
      a2+=e*__uint_as_float(u.y<<16);
      a3+=e*__uint_as_float(u.y&0xffff0000u);
    }
    a0+=__shfl_xor(a0,16,64); a0+=__shfl_xor(a0,32,64);
    a1+=__shfl_xor(a1,16,64); a1+=__shfl_xor(a1,32,64);
    a2+=__shfl_xor(a2,16,64); a2+=__shfl_xor(a2,32,64);
    a3+=__shfl_xor(a3,16,64); a3+=__shfl_xor(a3,32,64);
    if(lane<16){
      part[wid*64+lane*4+0]=a0; part[wid*64+lane*4+1]=a1;
      part[wid*64+lane*4+2]=a2; part[wid*64+lane*4+3]=a3;
    }
    __syncthreads();
    if(tid<64){
      float s2=0.f;
      #pragma unroll
      for(int w=0;w<16;w++) s2+=part[w*64+tid];
      upd[bk*64+tid]=s2*inv;
    }
  } else {
    float amax = inv;
    float amin = __expf(LMIN-LMAX)*inv;
    float dinv = 1.f/(amax-amin+1e-5f);
    #pragma unroll
    for(int i=0;i<4;i++){
      int n=tid+i*1024;
      out_attn[(size_t)bk*N_+n] = (ls[n]*inv - amin)*dinv;
    }
    int sub=lane>>4, c=lane&15;
    const float* Fb = featc + (size_t)b*N_*16;
    float a0=0.f;
    for(int t=0;t<64;t++){
      int n=(wid<<8)+(t<<2)+sub;
      a0 += ls[n]*Fb[(size_t)n*16+c];
    }
    a0+=__shfl_xor(a0,16,64); a0+=__shfl_xor(a0,32,64);
    if(lane<16) part[wid*16+lane]=a0;
    __syncthreads();
    if(tid<16){
      float s2=0.f;
      #pragma unroll
      for(int w=0;w<16;w++) s2+=part[w*16+tid];
      out_slot[bk*80+64+tid]=s2*inv;
    }
    if(tid<64) out_slot[bk*80+tid]=slot[bk*64+tid];
  }
}

// GRU cell + LN residual projection
__global__ __launch_bounds__(64) void k_gru(const float* __restrict__ upd, float* __restrict__ slot,
   const float* __restrict__ wih, const float* __restrict__ whh,
   const float* __restrict__ bih, const float* __restrict__ bhh,
   const float* __restrict__ lng, const float* __restrict__ lnb,
   const float* __restrict__ wres, const float* __restrict__ bres){
  int row=blockIdx.x; int lane=threadIdx.x;
  float x=upd[row*64+lane], hp=slot[row*64+lane];
  float gir=bih[lane], giz=bih[64+lane], gin=bih[128+lane];
  float ghr=bhh[lane], ghz=bhh[64+lane], ghn=bhh[128+lane];
  #pragma unroll
  for(int d=0;d<64;d++){
    float xd=__shfl(x,d,64), hd=__shfl(hp,d,64);
    gir+=xd*wih[lane*64+d];
    giz+=xd*wih[(64+lane)*64+d];
    gin+=xd*wih[(128+lane)*64+d];
    ghr+=hd*whh[lane*64+d];
    ghz+=hd*whh[(64+lane)*64+d];
    ghn+=hd*whh[(128+lane)*64+d];
  }
  float r=1.f/(1.f+expf(-(gir+ghr)));
  float z=1.f/(1.f+expf(-(giz+ghz)));
  float nn=tanhf(gin+r*ghn);
  float sp=(1.f-z)*nn+z*hp;
  float m=wsum64(sp)*(1.f/64.f); float df=sp-m;
  float var=wsum64(df*df)*(1.f/64.f);
  float xl=df*rsqrtf(var+EPS)*lng[lane]+lnb[lane];
  float a=bres[lane]+hp;
  #pragma unroll
  for(int d=0;d<64;d++) a+=__shfl(xl,d,64)*wres[lane*64+d];
  slot[row*64+lane]=a;
}

extern "C" void kernel_launch(void* const* d_in, const int* in_sizes, int n_in,
                              void* d_out, int out_size, void* d_ws, size_t ws_size,
                              hipStream_t stream){
  (void)in_sizes; (void)n_in; (void)out_size; (void)ws_size;
  const float* feat = (const float*)d_in[0];
  const float* featc= (const float*)d_in[1];
  const float* mask = (const float*)d_in[2];
  const float* noise= (const float*)d_in[3];
  const float* mu   = (const float*)d_in[4];
  const float* lsg  = (const float*)d_in[5];
  const float* wg   = (const float*)d_in[6];
  const float* bg   = (const float*)d_in[7];
  const float* wk   = (const float*)d_in[8];
  const float* wv   = (const float*)d_in[9];
  const float* lnkg = (const float*)d_in[10];
  const float* lnkb = (const float*)d_in[11];
  const float* wm   = (const float*)d_in[12];
  const float* bm   = (const float*)d_in[13];
  const float* lnqg = (const float*)d_in[14];
  const float* lnqb = (const float*)d_in[15];
  const float* wq   = (const float*)d_in[16];
  const float* wih  = (const float*)d_in[17];
  const float* whh  = (const float*)d_in[18];
  const float* bih  = (const float*)d_in[19];
  const float* bhh  = (const float*)d_in[20];
  const float* lnfg = (const float*)d_in[21];
  const float* lnfb = (const float*)d_in[22];
  const float* lncg = (const float*)d_in[23];
  const float* lncb = (const float*)d_in[24];
  const float* lnrg = (const float*)d_in[25];
  const float* lnrb = (const float*)d_in[26];
  const float* wres = (const float*)d_in[27];
  const float* bres = (const float*)d_in[28];

  float* out = (float*)d_out;
  float* out_slot = out;          // (B,K,80)
  float* out_fg   = out + 6400;   // (B,K,2)
  float* out_attn = out + 6560;   // (B,K,N)

  float* wsf    = (float*)d_ws;
  float* ws_fg  = wsf;                     // 16
  float* ws_ge  = wsf + 16;                // K*N*D
  float* ws_fk  = ws_ge + (size_t)K_*N_*D_;
  float* ws_fv  = ws_fk + (size_t)B_*N_*D_;
  float* ws_fc  = ws_fv + (size_t)B_*N_*D_;
  float* ws_sl  = ws_fc + (size_t)B_*N_*C_;
  float* ws_q   = ws_sl + B_*K_*D_;
  float* ws_up  = ws_q  + B_*K_*D_;
  uint16_t* wsK = (uint16_t*)(ws_up + B_*K_*D_);
  uint16_t* wsV = wsK + (size_t)B_*K_*N_*D_;

  k_init_slot<<<20,256,0,stream>>>(noise,mu,lsg,ws_sl);
  k_fgpos<<<K_,256,0,stream>>>(mask,ws_fg,out_fg);
  k_gridemb<<<(K_*N_*D_)/256,256,0,stream>>>(wg,bg,ws_fg,ws_ge);
  k_featln<<<(B_*N_)/64,256,0,stream>>>(feat,wk,wv,lnfg,lnfb,ws_fk,ws_fv);
  k_featcln<<<(B_*N_)/16,256,0,stream>>>(featc,lncg,lncb,ws_fc);
  k_buildkv<<<dim3(N_/64,K_,B_),256,0,stream>>>(ws_fk,ws_fv,ws_ge,lnkg,lnkb,wm,bm,wsK,wsV);

  for(int it=0; it<4; it++){
    k_q<<<B_*K_,64,0,stream>>>(ws_sl,lnqg,lnqb,wq,ws_q);
    if(it<3){
      k_attn<false><<<B_*K_,1024,0,stream>>>(wsK,wsV,ws_q,ws_fc,ws_sl,ws_up,out_slot,out_attn);
      k_gru<<<B_*K_,64,0,stream>>>(ws_up,ws_sl,wih,whh,bih,bhh,lnrg,lnrb,wres,bres);
    } else {
      k_attn<true><<<B_*K_,1024,0,stream>>>(wsK,wsV,ws_q,ws_fc,ws_sl,ws_up,out_slot,out_attn);
    }
  }
}

// Round 3
// 350.427 us; speedup vs baseline: 3.4658x; 1.3386x over previous
//
#include <hip/hip_runtime.h>
#include <stdint.h>

#define B_ 16
#define H_ 64
#define W_ 64
#define D_ 64
#define C_ 16
#define K_ 5
#define N_ 4096
#define NC_ 8          // attention n-chunks
#define CS_ 512        // chunk size = N_/NC_
#define EPS 1e-5f

typedef __attribute__((ext_vector_type(8))) short bf16x8;
typedef __attribute__((ext_vector_type(4))) float f32x4;

__device__ __forceinline__ float wsum64(float v){
  #pragma unroll
  for(int o=1;o<64;o<<=1) v += __shfl_xor(v,o,64);
  return v;
}
__device__ __forceinline__ float wmax64(float v){
  #pragma unroll
  for(int o=1;o<64;o<<=1) v = fmaxf(v, __shfl_xor(v,o,64));
  return v;
}
__device__ __forceinline__ float wmin64(float v){
  #pragma unroll
  for(int o=1;o<64;o<<=1) v = fminf(v, __shfl_xor(v,o,64));
  return v;
}
__device__ __forceinline__ uint16_t f2bf(float f){
  uint32_t u = __float_as_uint(f);
  u += 0x7fffu + ((u>>16)&1u);
  return (uint16_t)(u>>16);
}
__device__ __forceinline__ void bf8_to_f(uint4 u, float* x){
  x[0]=__uint_as_float(u.x<<16); x[1]=__uint_as_float(u.x&0xffff0000u);
  x[2]=__uint_as_float(u.y<<16); x[3]=__uint_as_float(u.y&0xffff0000u);
  x[4]=__uint_as_float(u.z<<16); x[5]=__uint_as_float(u.z&0xffff0000u);
  x[6]=__uint_as_float(u.w<<16); x[7]=__uint_as_float(u.w&0xffff0000u);
}

// slot = mu + exp(logsigma) * noise
__global__ void k_init_slot(const float* __restrict__ noise, const float* __restrict__ mu,
                            const float* __restrict__ ls, float* __restrict__ slot){
  int i = blockIdx.x*256 + threadIdx.x;
  if(i >= B_*K_*D_) return;
  int d = i & 63;
  slot[i] = mu[d] + expf(ls[d])*noise[i];
}

// fg_pos (K,2): weighted mean of grid under mask
__global__ void k_fgpos(const float* __restrict__ mask, float* __restrict__ ws_fg,
                        float* __restrict__ out_fg){
  int k = blockIdx.x; int tid = threadIdx.x;
  float sm=0.f, sx=0.f, sy=0.f;
  for(int p=tid; p<H_*W_; p+=256){
    int i=p>>6, j=p&63;
    float m = mask[k*H_*W_ + p];
    float x = -1.f + (2.f/63.f)*j;
    float y = -1.f + (2.f/63.f)*i;
    sm+=m; sx+=m*x; sy+=m*y;
  }
  __shared__ float r0[4], r1[4], r2[4];
  int wid=tid>>6, lane=tid&63;
  sm=wsum64(sm); sx=wsum64(sx); sy=wsum64(sy);
  if(lane==0){ r0[wid]=sm; r1[wid]=sx; r2[wid]=sy; }
  __syncthreads();
  if(tid==0){
    float tm=r0[0]+r0[1]+r0[2]+r0[3];
    float tx=r1[0]+r1[1]+r1[2]+r1[3];
    float ty=r2[0]+r2[1]+r2[2]+r2[3];
    float px = tx/(tm+1e-5f), py = ty/(tm+1e-5f);
    ws_fg[k*2+0]=px; ws_fg[k*2+1]=py;
    for(int b=0;b<B_;b++){ out_fg[(b*K_+k)*2+0]=px; out_fg[(b*K_+k)*2+1]=py; }
  }
}

// grid_embed (K,N,D)
__global__ void k_gridemb(const float* __restrict__ wg, const float* __restrict__ bg,
                          const float* __restrict__ ws_fg, float* __restrict__ ge){
  int idx = blockIdx.x*256 + threadIdx.x;
  int d = idx & 63;
  int n = (idx>>6) & (N_-1);
  int k = idx >> 18;
  int j = n & 63, i = n >> 6;
  float rx = (-1.f + (2.f/63.f)*j) - ws_fg[k*2+0];
  float ry = (-1.f + (2.f/63.f)*i) - ws_fg[k*2+1];
  ge[idx] = rx*(wg[d*4+0]-wg[d*4+2]) + ry*(wg[d*4+1]-wg[d*4+3]) + bg[d];
}

// feat LN + fk = featn@w_k.T, fv = featn@w_v.T  (MFMA, bf16 output)
__global__ __launch_bounds__(256) void k_featln(const float* __restrict__ feat,
    const float* __restrict__ wk, const float* __restrict__ wv,
    const float* __restrict__ g, const float* __restrict__ bb,
    uint16_t* __restrict__ fk, uint16_t* __restrict__ fv){
  int tid=threadIdx.x, wid=tid>>6, lane=tid&63;
  int q=lane>>4, c=lane&15;
  size_t row = (size_t)blockIdx.x*64 + wid*16 + c;
  const float* xp = feat + row*64;
  float x[16];
  *(float4*)&x[0]  = *(const float4*)(xp + q*8);
  *(float4*)&x[4]  = *(const float4*)(xp + q*8 + 4);
  *(float4*)&x[8]  = *(const float4*)(xp + 32 + q*8);
  *(float4*)&x[12] = *(const float4*)(xp + 36 + q*8);
  float s=0.f;
  #pragma unroll
  for(int i=0;i<16;i++) s+=x[i];
  s += __shfl_xor(s,16,64); s += __shfl_xor(s,32,64);
  float mean = s*(1.f/64.f);
  float v=0.f;
  #pragma unroll
  for(int i=0;i<16;i++){ float d=x[i]-mean; v+=d*d; }
  v += __shfl_xor(v,16,64); v += __shfl_xor(v,32,64);
  float rs = rsqrtf(v*(1.f/64.f)+EPS);
  float gl[16], bl[16];
  *(float4*)&gl[0]  = *(const float4*)(g + q*8);
  *(float4*)&gl[4]  = *(const float4*)(g + q*8 + 4);
  *(float4*)&gl[8]  = *(const float4*)(g + 32 + q*8);
  *(float4*)&gl[12] = *(const float4*)(g + 36 + q*8);
  *(float4*)&bl[0]  = *(const float4*)(bb + q*8);
  *(float4*)&bl[4]  = *(const float4*)(bb + q*8 + 4);
  *(float4*)&bl[8]  = *(const float4*)(bb + 32 + q*8);
  *(float4*)&bl[12] = *(const float4*)(bb + 36 + q*8);
  bf16x8 A0, A1;
  #pragma unroll
  for(int j=0;j<8;j++){
    A0[j] = (short)f2bf((x[j]  -mean)*rs*gl[j]  +bl[j]);
    A1[j] = (short)f2bf((x[8+j]-mean)*rs*gl[8+j]+bl[8+j]);
  }
  #pragma unroll
  for(int mat=0;mat<2;mat++){
    const float* w = mat? wv : wk;
    uint16_t* o = (mat? fv : fk) + row*64;
    #pragma unroll
    for(int ot=0; ot<4; ot++){
      const float* wp = w + (size_t)(ot*16+c)*64 + q*8;
      bf16x8 W0, W1;
      #pragma unroll
      for(int j=0;j<8;j++){ W0[j]=(short)f2bf(wp[j]); W1[j]=(short)f2bf(wp[32+j]); }
      f32x4 acc = {0.f,0.f,0.f,0.f};
      acc = __builtin_amdgcn_mfma_f32_16x16x32_bf16(W0, A0, acc, 0,0,0);
      acc = __builtin_amdgcn_mfma_f32_16x16x32_bf16(W1, A1, acc, 0,0,0);
      uint2 u;
      u.x = (uint32_t)f2bf(acc[0]) | ((uint32_t)f2bf(acc[1])<<16);
      u.y = (uint32_t)f2bf(acc[2]) | ((uint32_t)f2bf(acc[3])<<16);
      *(uint2*)(o + ot*16 + q*4) = u;
    }
  }
}

// feat_color LN over C=16
__global__ void k_featcln(const float* __restrict__ fc, const float* __restrict__ g,
                          const float* __restrict__ b, float* __restrict__ out){
  int tid=threadIdx.x;
  int row = blockIdx.x*16 + (tid>>4);
  int c = tid&15;
  float x = fc[(size_t)row*16+c];
  float s=x;
  #pragma unroll
  for(int o=1;o<16;o<<=1) s += __shfl_xor(s,o,16);
  float m = s*(1.f/16.f);
  float df = x-m;
  float v2 = df*df;
  #pragma unroll
  for(int o=1;o<16;o<<=1) v2 += __shfl_xor(v2,o,16);
  out[(size_t)row*16+c] = df*rsqrtf(v2*(1.f/16.f)+EPS)*g[c] + b[c];
}

// K/V = LN(f{k,v}+ge)@w_mlp.T + b_mlp -> bf16. MFMA; 4 row-tiles per wave,
// weight fragments hoisted (converted once per block).
__global__ __launch_bounds__(256) void k_buildkv(const uint16_t* __restrict__ fk,
    const uint16_t* __restrict__ fv, const float* __restrict__ ge,
    const float* __restrict__ lng, const float* __restrict__ lnb,
    const float* __restrict__ wm, const float* __restrict__ bm,
    uint16_t* __restrict__ Kw, uint16_t* __restrict__ Vw){
  int tid=threadIdx.x, wid=tid>>6, lane=tid&63;
  int q=lane>>4, c=lane&15;
  int k = blockIdx.y, b = blockIdx.z;
  bf16x8 Wf[4][2];
  #pragma unroll
  for(int ot=0;ot<4;ot++){
    const float* wp = wm + (size_t)(ot*16+c)*64 + q*8;
    #pragma unroll
    for(int j=0;j<8;j++){ Wf[ot][0][j]=(short)f2bf(wp[j]); Wf[ot][1][j]=(short)f2bf(wp[32+j]); }
  }
  float bmv[4][4];
  #pragma unroll
  for(int ot=0;ot<4;ot++) *(float4*)&bmv[ot][0] = *(const float4*)(bm + ot*16 + q*4);
  float gl[16], bl[16];
  *(float4*)&gl[0]  = *(const float4*)(lng + q*8);
  *(float4*)&gl[4]  = *(const float4*)(lng + q*8 + 4);
  *(float4*)&gl[8]  = *(const float4*)(lng + 32 + q*8);
  *(float4*)&gl[12] = *(const float4*)(lng + 36 + q*8);
  *(float4*)&bl[0]  = *(const float4*)(lnb + q*8);
  *(float4*)&bl[4]  = *(const float4*)(lnb + q*8 + 4);
  *(float4*)&bl[8]  = *(const float4*)(lnb + 32 + q*8);
  *(float4*)&bl[12] = *(const float4*)(lnb + 36 + q*8);

  for(int t=0;t<4;t++){
    int n = blockIdx.x*256 + t*64 + wid*16 + c;
    const float* gp = ge + ((size_t)k*N_ + n)*64;
    float ga[16];
    *(float4*)&ga[0]  = *(const float4*)(gp + q*8);
    *(float4*)&ga[4]  = *(const float4*)(gp + q*8 + 4);
    *(float4*)&ga[8]  = *(const float4*)(gp + 32 + q*8);
    *(float4*)&ga[12] = *(const float4*)(gp + 36 + q*8);
    #pragma unroll
    for(int mat=0;mat<2;mat++){
      const uint16_t* fp = (mat? fv : fk) + ((size_t)b*N_ + n)*64;
      float x[16];
      bf8_to_f(*(const uint4*)(fp + q*8), &x[0]);
      bf8_to_f(*(const uint4*)(fp + 32 + q*8), &x[8]);
      #pragma unroll
      for(int i=0;i<16;i++) x[i]+=ga[i];
      float s=0.f;
      #pragma unroll
      for(int i=0;i<16;i++) s+=x[i];
      s += __shfl_xor(s,16,64); s += __shfl_xor(s,32,64);
      float mean = s*(1.f/64.f);
      float v=0.f;
      #pragma unroll
      for(int i=0;i<16;i++){ float d=x[i]-mean; v+=d*d; }
      v += __shfl_xor(v,16,64); v += __shfl_xor(v,32,64);
      float rs = rsqrtf(v*(1.f/64.f)+EPS);
      bf16x8 A0, A1;
      #pragma unroll
      for(int j=0;j<8;j++){
        A0[j] = (short)f2bf((x[j]  -mean)*rs*gl[j]  +bl[j]);
        A1[j] = (short)f2bf((x[8+j]-mean)*rs*gl[8+j]+bl[8+j]);
      }
      uint16_t* outb = (mat? Vw : Kw) + (((size_t)(b*K_+k))*N_)*64;
      #pragma unroll
      for(int ot=0; ot<4; ot++){
        f32x4 acc = {0.f,0.f,0.f,0.f};
        acc = __builtin_amdgcn_mfma_f32_16x16x32_bf16(Wf[ot][0], A0, acc, 0,0,0);
        acc = __builtin_amdgcn_mfma_f32_16x16x32_bf16(Wf[ot][1], A1, acc, 0,0,0);
        uint2 u;
        u.x = (uint32_t)f2bf(acc[0]+bmv[ot][0]) | ((uint32_t)f2bf(acc[1]+bmv[ot][1])<<16);
        u.y = (uint32_t)f2bf(acc[2]+bmv[ot][2]) | ((uint32_t)f2bf(acc[3]+bmv[ot][3])<<16);
        *(uint2*)(outb + (size_t)n*64 + ot*16 + q*4) = u;
      }
    }
  }
}

// q = LN(slot)@w_q.T, pre-scaled by d^-0.5
__global__ __launch_bounds__(64) void k_q(const float* __restrict__ slot,
    const float* __restrict__ g, const float* __restrict__ b,
    const float* __restrict__ wq, float* __restrict__ q){
  int row=blockIdx.x; int lane=threadIdx.x;
  float x = slot[row*64+lane];
  float m=wsum64(x)*(1.f/64.f); float df=x-m;
  float var=wsum64(df*df)*(1.f/64.f);
  float xl=df*rsqrtf(var+EPS)*g[lane]+b[lane];
  float a=0.f;
  #pragma unroll
  for(int d=0;d<64;d++) a += __shfl(xl,d,64)*wq[lane*64+d];
  q[row*64+lane]=a*0.125f;
}

// logits for one n-chunk + chunk-local softmax stats (m, sum, [min])
template<bool FINAL>
__global__ __launch_bounds__(256) void k_logits(const uint16_t* __restrict__ Kw,
    const float* __restrict__ q, float* __restrict__ lgt, float* __restrict__ red){
  __shared__ float qs[64];
  __shared__ float rm[4], rs_[4], rn[4];
  int chunk=blockIdx.x, bk=blockIdx.y;
  int tid=threadIdx.x, wid=tid>>6, lane=tid&63;
  if(tid<64) qs[tid]=q[bk*64+tid];
  __syncthreads();
  const uint4* Kb = (const uint4*)(Kw + (size_t)bk*N_*64) + (size_t)chunk*CS_*8;
  float l[2];
  #pragma unroll
  for(int i=0;i<2;i++){
    int n = tid + i*256;
    float a=0.f;
    #pragma unroll
    for(int j=0;j<8;j++){
      uint4 u = Kb[(size_t)n*8+j];
      a += __uint_as_float(u.x<<16)          * qs[j*8+0]
         + __uint_as_float(u.x&0xffff0000u)  * qs[j*8+1]
         + __uint_as_float(u.y<<16)          * qs[j*8+2]
         + __uint_as_float(u.y&0xffff0000u)  * qs[j*8+3]
         + __uint_as_float(u.z<<16)          * qs[j*8+4]
         + __uint_as_float(u.z&0xffff0000u)  * qs[j*8+5]
         + __uint_as_float(u.w<<16)          * qs[j*8+6]
         + __uint_as_float(u.w&0xffff0000u)  * qs[j*8+7];
    }
    l[i]=a;
    lgt[(size_t)bk*N_ + chunk*CS_ + n] = a;
  }
  float wm_ = wmax64(fmaxf(l[0],l[1]));
  if(lane==0) rm[wid]=wm_;
  if(FINAL){ float mn=wmin64(fminf(l[0],l[1])); if(lane==0) rn[wid]=mn; }
  __syncthreads();
  float m_c = fmaxf(fmaxf(rm[0],rm[1]),fmaxf(rm[2],rm[3]));
  float s = __expf(l[0]-m_c)+__expf(l[1]-m_c);
  s = wsum64(s);
  if(lane==0) rs_[wid]=s;
  __syncthreads();
  if(tid==0){
    float* rp = red + ((size_t)bk*NC_+chunk)*4;
    rp[0]=m_c;
    rp[1]=rs_[0]+rs_[1]+rs_[2]+rs_[3];
    if(FINAL) rp[2]=fminf(fminf(rn[0],rn[1]),fminf(rn[2],rn[3]));
  }
}

// p = exp(l-M)/S for one chunk; partial upd = p@V (and FINAL: p@featc, out_attn)
template<bool FINAL>
__global__ __launch_bounds__(256) void k_updv(const uint16_t* __restrict__ Vw,
    const float* __restrict__ lgt, const float* __restrict__ red,
    const float* __restrict__ featc,
    float* __restrict__ part, float* __restrict__ partc, float* __restrict__ out_attn){
  __shared__ float ps[CS_];
  __shared__ float pw[4][64];
  __shared__ float pcz[4][16];
  int chunk=blockIdx.x, bk=blockIdx.y, b=bk/K_;
  int tid=threadIdx.x, wid=tid>>6, lane=tid&63, sub=lane>>4, c4=lane&15;
  const float* rp = red + (size_t)bk*NC_*4;
  float M=-1e30f;
  #pragma unroll
  for(int i=0;i<NC_;i++) M = fmaxf(M, rp[i*4]);
  float S=0.f;
  #pragma unroll
  for(int i=0;i<NC_;i++) S += rp[i*4+1]*__expf(rp[i*4]-M);
  float invS = 1.f/S;
  float amin=0.f, dinv=0.f;
  if(FINAL){
    float LMIN=1e30f;
    #pragma unroll
    for(int i=0;i<NC_;i++) LMIN=fminf(LMIN, rp[i*4+2]);
    amin = __expf(LMIN-M)*invS;
    dinv = 1.f/(invS - amin + 1e-5f);
  }
  const float* lp = lgt + (size_t)bk*N_ + chunk*CS_;
  #pragma unroll
  for(int i=0;i<2;i++){
    int n = tid + i*256;
    float p = __expf(lp[n]-M)*invS;
    ps[n]=p;
    if(FINAL) out_attn[(size_t)bk*N_ + chunk*CS_ + n] = (p - amin)*dinv;
  }
  __syncthreads();
  const uint2* Vb = (const uint2*)(Vw + (size_t)bk*N_*64) + (size_t)chunk*CS_*16;
  const float* Fb = featc + ((size_t)b*N_ + chunk*CS_)*16;
  float a0=0.f,a1=0.f,a2=0.f,a3=0.f,ac=0.f;
  for(int t=0;t<32;t++){
    int n = wid*128 + t*4 + sub;
    float p = ps[n];
    uint2 u = Vb[(size_t)n*16 + c4];
    a0 += p*__uint_as_float(u.x<<16);
    a1 += p*__uint_as_float(u.x&0xffff0000u);
    a2 += p*__uint_as_float(u.y<<16);
    a3 += p*__uint_as_float(u.y&0xffff0000u);
    if(FINAL) ac += p*Fb[(size_t)n*16 + c4];
  }
  a0+=__shfl_xor(a0,16,64); a0+=__shfl_xor(a0,32,64);
  a1+=__shfl_xor(a1,16,64); a1+=__shfl_xor(a1,32,64);
  a2+=__shfl_xor(a2,16,64); a2+=__shfl_xor(a2,32,64);
  a3+=__shfl_xor(a3,16,64); a3+=__shfl_xor(a3,32,64);
  if(FINAL){ ac+=__shfl_xor(ac,16,64); ac+=__shfl_xor(ac,32,64); }
  if(lane<16){
    pw[wid][lane*4+0]=a0; pw[wid][lane*4+1]=a1;
    pw[wid][lane*4+2]=a2; pw[wid][lane*4+3]=a3;
    if(FINAL) pcz[wid][lane]=ac;
  }
  __syncthreads();
  if(tid<64){
    part[((size_t)bk*NC_+chunk)*64 + tid] = pw[0][tid]+pw[1][tid]+pw[2][tid]+pw[3][tid];
  }
  if(FINAL && tid<16){
    partc[((size_t)bk*NC_+chunk)*16 + tid] = pcz[0][tid]+pcz[1][tid]+pcz[2][tid]+pcz[3][tid];
  }
}

// GRU cell + LN residual projection (reads chunk partials for upd)
__global__ __launch_bounds__(64) void k_gru(const float* __restrict__ part, float* __restrict__ slot,
   const float* __restrict__ wih, const float* __restrict__ whh,
   const float* __restrict__ bih, const float* __restrict__ bhh,
   const float* __restrict__ lng, const float* __restrict__ lnb,
   const float* __restrict__ wres, const float* __restrict__ bres){
  int row=blockIdx.x; int lane=threadIdx.x;
  float x=0.f;
  #pragma unroll
  for(int cch=0;cch<NC_;cch++) x += part[((size_t)row*NC_+cch)*64+lane];
  float hp=slot[row*64+lane];
  float gir=bih[lane], giz=bih[64+lane], gin=bih[128+lane];
  float ghr=bhh[lane], ghz=bhh[64+lane], ghn=bhh[128+lane];
  #pragma unroll
  for(int d=0;d<64;d++){
    float xd=__shfl(x,d,64), hd=__shfl(hp,d,64);
    gir+=xd*wih[lane*64+d];
    giz+=xd*wih[(64+lane)*64+d];
    gin+=xd*wih[(128+lane)*64+d];
    ghr+=hd*whh[lane*64+d];
    ghz+=hd*whh[(64+lane)*64+d];
    ghn+=hd*whh[(128+lane)*64+d];
  }
  float r=1.f/(1.f+expf(-(gir+ghr)));
  float z=1.f/(1.f+expf(-(giz+ghz)));
  float nn=tanhf(gin+r*ghn);
  float sp=(1.f-z)*nn+z*hp;
  float m=wsum64(sp)*(1.f/64.f); float df=sp-m;
  float var=wsum64(df*df)*(1.f/64.f);
  float xl=df*rsqrtf(var+EPS)*lng[lane]+lnb[lane];
  float a=bres[lane]+hp;
  #pragma unroll
  for(int d=0;d<64;d++) a+=__shfl(xl,d,64)*wres[lane*64+d];
  slot[row*64+lane]=a;
}

// final: out_slot = [slot, sum of color partials]
__global__ __launch_bounds__(64) void k_final(const float* __restrict__ slot,
    const float* __restrict__ partc, float* __restrict__ out_slot){
  int bk=blockIdx.x, lane=threadIdx.x;
  out_slot[bk*80+lane]=slot[bk*64+lane];
  if(lane<16){
    float s=0.f;
    #pragma unroll
    for(int cch=0;cch<NC_;cch++) s += partc[((size_t)bk*NC_+cch)*16+lane];
    out_slot[bk*80+64+lane]=s;
  }
}

extern "C" void kernel_launch(void* const* d_in, const int* in_sizes, int n_in,
                              void* d_out, int out_size, void* d_ws, size_t ws_size,
                              hipStream_t stream){
  (void)in_sizes; (void)n_in; (void)out_size; (void)ws_size;
  const float* feat = (const float*)d_in[0];
  const float* featc= (const float*)d_in[1];
  const float* mask = (const float*)d_in[2];
  const float* noise= (const float*)d_in[3];
  const float* mu   = (const float*)d_in[4];
  const float* lsg  = (const float*)d_in[5];
  const float* wg   = (const float*)d_in[6];
  const float* bg   = (const float*)d_in[7];
  const float* wk   = (const float*)d_in[8];
  const float* wv   = (const float*)d_in[9];
  const float* lnkg = (const float*)d_in[10];
  const float* lnkb = (const float*)d_in[11];
  const float* wm   = (const float*)d_in[12];
  const float* bm   = (const float*)d_in[13];
  const float* lnqg = (const float*)d_in[14];
  const float* lnqb = (const float*)d_in[15];
  const float* wq   = (const float*)d_in[16];
  const float* wih  = (const float*)d_in[17];
  const float* whh  = (const float*)d_in[18];
  const float* bih  = (const float*)d_in[19];
  const float* bhh  = (const float*)d_in[20];
  const float* lnfg = (const float*)d_in[21];
  const float* lnfb = (const float*)d_in[22];
  const float* lncg = (const float*)d_in[23];
  const float* lncb = (const float*)d_in[24];
  const float* lnrg = (const float*)d_in[25];
  const float* lnrb = (const float*)d_in[26];
  const float* wres = (const float*)d_in[27];
  const float* bres = (const float*)d_in[28];

  float* out = (float*)d_out;
  float* out_slot = out;          // (B,K,80)
  float* out_fg   = out + 6400;   // (B,K,2)
  float* out_attn = out + 6560;   // (B,K,N)

  float* wsf     = (float*)d_ws;
  float* ws_fg   = wsf;                                // 16
  float* ws_ge   = wsf + 16;                           // K*N*D
  float* ws_fc   = ws_ge + (size_t)K_*N_*D_;           // B*N*C
  float* ws_sl   = ws_fc + (size_t)B_*N_*C_;           // 5120
  float* ws_q    = ws_sl + B_*K_*D_;                   // 5120
  float* ws_lgt  = ws_q  + B_*K_*D_;                   // B*K*N
  float* ws_red  = ws_lgt + (size_t)B_*K_*N_;          // 80*NC*4
  float* ws_part = ws_red + B_*K_*NC_*4;               // 80*NC*64
  float* ws_pc   = ws_part + (size_t)B_*K_*NC_*64;     // 80*NC*16
  uint16_t* ws_fkb = (uint16_t*)(ws_pc + B_*K_*NC_*16);
  uint16_t* ws_fvb = ws_fkb + (size_t)B_*N_*D_;
  uint16_t* wsK    = ws_fvb + (size_t)B_*N_*D_;
  uint16_t* wsV    = wsK + (size_t)B_*K_*N_*D_;

  k_init_slot<<<20,256,0,stream>>>(noise,mu,lsg,ws_sl);
  k_fgpos<<<K_,256,0,stream>>>(mask,ws_fg,out_fg);
  k_gridemb<<<(K_*N_*D_)/256,256,0,stream>>>(wg,bg,ws_fg,ws_ge);
  k_featln<<<(B_*N_)/64,256,0,stream>>>(feat,wk,wv,lnfg,lnfb,ws_fkb,ws_fvb);
  k_featcln<<<(B_*N_)/16,256,0,stream>>>(featc,lncg,lncb,ws_fc);
  k_buildkv<<<dim3(N_/256,K_,B_),256,0,stream>>>(ws_fkb,ws_fvb,ws_ge,lnkg,lnkb,wm,bm,wsK,wsV);

  for(int it=0; it<4; it++){
    k_q<<<B_*K_,64,0,stream>>>(ws_sl,lnqg,lnqb,wq,ws_q);
    if(it<3){
      k_logits<false><<<dim3(NC_,B_*K_),256,0,stream>>>(wsK,ws_q,ws_lgt,ws_red);
      k_updv<false><<<dim3(NC_,B_*K_),256,0,stream>>>(wsV,ws_lgt,ws_red,ws_fc,ws_part,ws_pc,out_attn);
      k_gru<<<B_*K_,64,0,stream>>>(ws_part,ws_sl,wih,whh,bih,bhh,lnrg,lnrb,wres,bres);
    } else {
      k_logits<true><<<dim3(NC_,B_*K_),256,0,stream>>>(wsK,ws_q,ws_lgt,ws_red);
      k_updv<true><<<dim3(NC_,B_*K_),256,0,stream>>>(wsV,ws_lgt,ws_red,ws_fc,ws_part,ws_pc,out_attn);
      k_final<<<B_*K_,64,0,stream>>>(ws_sl,ws_pc,out_slot);
    }
  }
}